// Round 1
// baseline (3780.918 us; speedup 1.0000x reference)
//
#include <hip/hip_runtime.h>

// Problem constants
#define V_ 32000
#define D_ 512
#define R_ 512
#define E_ 512
#define B_ 32
#define T_ 64
#define S_ 64
#define BT_ (B_ * T_)   // 2048
#define G3_ (3 * R_)    // 1536

typedef __bf16 bf16x8 __attribute__((ext_vector_type(8)));
typedef float f32x4 __attribute__((ext_vector_type(4)));

__device__ __forceinline__ float dot4(float4 a, float4 b) {
    return a.x * b.x + a.y * b.y + a.z * b.z + a.w * b.w;
}
__device__ __forceinline__ float sigmoidf_(float x) {
    return 1.0f / (1.0f + __expf(-x));
}

// ---------------- fp32 -> bf16 convert (8 elems/thread) ----------------
__global__ __launch_bounds__(256) void k_convert_bf16(const float* __restrict__ src,
                                                      __bf16* __restrict__ dst, int n8) {
    int i = blockIdx.x * 256 + threadIdx.x;
    if (i >= n8) return;
    float4 a = *(const float4*)&src[(size_t)i * 8];
    float4 b = *(const float4*)&src[(size_t)i * 8 + 4];
    bf16x8 o;
    o[0] = (__bf16)a.x; o[1] = (__bf16)a.y; o[2] = (__bf16)a.z; o[3] = (__bf16)a.w;
    o[4] = (__bf16)b.x; o[5] = (__bf16)b.y; o[6] = (__bf16)b.z; o[7] = (__bf16)b.w;
    *(bf16x8*)&dst[(size_t)i * 8] = o;
}

// ---------------- gather embedding rows for trg (bf16) ----------------
__global__ __launch_bounds__(256) void k_gather_emb(const int* __restrict__ trg,
                                                    const __bf16* __restrict__ embW,
                                                    __bf16* __restrict__ dst) {
    int id = blockIdx.x * 256 + threadIdx.x;  // BT_*64 threads (8 bf16 each)
    int bt = id >> 6, c = id & 63;
    int tok = trg[bt];
    *(uint4*)&dst[(size_t)bt * 512 + c * 8] = *(const uint4*)&embW[(size_t)tok * 512 + c * 8];
}

// ---------------- bf16 MFMA GEMM: C = A[M,K] * B^T[N,K] (+bias) ----------------
// 128x128 tile, BK=32, 4 waves (2x2), per-wave 64x64 = 4x4 frags of 16x16x32.
// mode 0: out[row*N + col] = v   (row-major f32)
// mode 1: out[(t*1536 + col)*32 + b] = v   with row = b*64 + t   (gxe scatter)
__global__ __launch_bounds__(256) void k_gemm_bf16(const __bf16* __restrict__ A,
                                                   const __bf16* __restrict__ B,
                                                   const float* __restrict__ bias,
                                                   float* __restrict__ out,
                                                   int M, int N, int K, int lda, int ldb,
                                                   int mode) {
    __shared__ __bf16 lA[128 * 32];
    __shared__ __bf16 lB[128 * 32];
    const int Mt = M >> 7;
    const int mt = blockIdx.x % Mt, nt = blockIdx.x / Mt;
    const int m0 = mt << 7, n0 = nt << 7;
    const int tid = threadIdx.x;
    const int w = tid >> 6, ln = tid & 63;
    const int wm = w >> 1, wn = w & 1;

    f32x4 acc[4][4];
#pragma unroll
    for (int mi = 0; mi < 4; ++mi)
#pragma unroll
        for (int ni = 0; ni < 4; ++ni) acc[mi][ni] = (f32x4){0.f, 0.f, 0.f, 0.f};

    const int k0 = (ln >> 4) * 8, rr = ln & 15;

    for (int kk = 0; kk < K; kk += 32) {
        __syncthreads();
#pragma unroll
        for (int p = 0; p < 2; ++p) {
            int i = p * 256 + tid;
            int r = i >> 2, q = i & 3;
            *(uint4*)&lA[r * 32 + q * 8] = *(const uint4*)&A[(size_t)(m0 + r) * lda + kk + q * 8];
            *(uint4*)&lB[r * 32 + q * 8] = *(const uint4*)&B[(size_t)(n0 + r) * ldb + kk + q * 8];
        }
        __syncthreads();
        bf16x8 af[4], bf[4];
#pragma unroll
        for (int mi = 0; mi < 4; ++mi) af[mi] = *(bf16x8*)&lA[(wm * 64 + mi * 16 + rr) * 32 + k0];
#pragma unroll
        for (int ni = 0; ni < 4; ++ni) bf[ni] = *(bf16x8*)&lB[(wn * 64 + ni * 16 + rr) * 32 + k0];
#pragma unroll
        for (int mi = 0; mi < 4; ++mi)
#pragma unroll
            for (int ni = 0; ni < 4; ++ni)
                acc[mi][ni] = __builtin_amdgcn_mfma_f32_16x16x32_bf16(af[mi], bf[ni], acc[mi][ni], 0, 0, 0);
    }

    const int rq = ln >> 4;
#pragma unroll
    for (int mi = 0; mi < 4; ++mi) {
#pragma unroll
        for (int ni = 0; ni < 4; ++ni) {
            int col = n0 + wn * 64 + ni * 16 + rr;
            float bv = bias ? bias[col] : 0.f;
#pragma unroll
            for (int reg = 0; reg < 4; ++reg) {
                int row = m0 + wm * 64 + mi * 16 + rq * 4 + reg;
                float v = acc[mi][ni][reg] + bv;
                if (mode == 0) {
                    out[(size_t)row * N + col] = v;
                } else {
                    int bb = row >> 6, tt = row & 63;
                    out[((size_t)tt * G3_ + col) * B_ + bb] = v;
                }
            }
        }
    }
}

// ---------------- stepA: GRU cell -> h_new  ----------------
// grid 128 wgs x 512 thr. wg owns j-slice of 4. thread = (kq[4], jl[4], b[32]).
// State h_prev, o_prev staged in LDS as [b][k] (padded rows).
__global__ __launch_bounds__(512, 1) void k_stepA(const float* __restrict__ hsrc,
                                                  const float* __restrict__ o_lin,
                                                  const float* __restrict__ Wih,
                                                  const float* __restrict__ Whh,
                                                  const float* __restrict__ bhh,
                                                  const float* __restrict__ gxe_t,  // [1536][32]
                                                  float* __restrict__ hdst) {
    __shared__ float hl[32][516];
    __shared__ float ol[32][516];
    __shared__ float red[6][4][4][32];  // gate, kq, jl, b
    const int tid = threadIdx.x;

    // stage h_prev and o_prev (32x512 f32 each)
#pragma unroll
    for (int p = 0; p < 8; ++p) {
        int f = p * 512 + tid;       // float4 index, 4096 total
        int row = f >> 7, c4 = f & 127;
        *(float4*)&hl[row][c4 * 4] = *(const float4*)&hsrc[(size_t)row * 512 + c4 * 4];
        *(float4*)&ol[row][c4 * 4] = *(const float4*)&o_lin[(size_t)row * 512 + c4 * 4];
    }
    __syncthreads();

    const int kq = tid >> 7, jl = (tid >> 5) & 3, b = tid & 31;
    const int j = blockIdx.x * 4 + jl;
    const float* wi_r = Wih + (size_t)j * 1024 + 512;      // o_prev part of W_ih
    const float* wi_z = wi_r + (size_t)512 * 1024;
    const float* wi_n = wi_r + (size_t)1024 * 1024;
    const float* wh_r = Whh + (size_t)j * 512;
    const float* wh_z = wh_r + (size_t)512 * 512;
    const float* wh_n = wh_r + (size_t)1024 * 512;

    float ar = 0, az = 0, an = 0, br = 0, bz = 0, bn = 0;
    const int kbase = kq * 128;
#pragma unroll 4
    for (int k = kbase; k < kbase + 128; k += 4) {
        float4 ov = *(const float4*)&ol[b][k];
        float4 hv = *(const float4*)&hl[b][k];
        float4 w1 = *(const float4*)&wi_r[k];
        float4 w2 = *(const float4*)&wi_z[k];
        float4 w3 = *(const float4*)&wi_n[k];
        float4 w4 = *(const float4*)&wh_r[k];
        float4 w5 = *(const float4*)&wh_z[k];
        float4 w6 = *(const float4*)&wh_n[k];
        ar += dot4(w1, ov); az += dot4(w2, ov); an += dot4(w3, ov);
        br += dot4(w4, hv); bz += dot4(w5, hv); bn += dot4(w6, hv);
    }
    red[0][kq][jl][b] = ar; red[1][kq][jl][b] = az; red[2][kq][jl][b] = an;
    red[3][kq][jl][b] = br; red[4][kq][jl][b] = bz; red[5][kq][jl][b] = bn;
    __syncthreads();

    if (tid < 128) {
        int jl2 = tid >> 5, b2 = tid & 31;
        int j2 = blockIdx.x * 4 + jl2;
        float s[6];
#pragma unroll
        for (int g = 0; g < 6; ++g) {
            s[g] = red[g][0][jl2][b2] + red[g][1][jl2][b2] + red[g][2][jl2][b2] + red[g][3][jl2][b2];
        }
        float gx_r = gxe_t[(size_t)j2 * 32 + b2] + s[0];
        float gx_z = gxe_t[(size_t)(j2 + 512) * 32 + b2] + s[1];
        float gx_n = gxe_t[(size_t)(j2 + 1024) * 32 + b2] + s[2];
        float gh_r = s[3] + bhh[j2];
        float gh_z = s[4] + bhh[j2 + 512];
        float gh_n = s[5] + bhh[j2 + 1024];
        float r = sigmoidf_(gx_r + gh_r);
        float z = sigmoidf_(gx_z + gh_z);
        float n = tanhf(gx_n + r * gh_n);
        float hprev = hl[b2][j2];
        hdst[(size_t)b2 * 512 + j2] = (1.0f - z) * n + z * hprev;
    }
}

// ---------------- stepB: attention + output projection ----------------
// grid 64 wgs x 256 thr: wg = (b, d-half)
__global__ __launch_bounds__(256) void k_stepB(const float* __restrict__ hcur,
                                               const float* __restrict__ encproj,  // [2048][512]
                                               const float* __restrict__ enc,      // [2048][512]
                                               const float* __restrict__ mask,     // [32][64]
                                               const float* __restrict__ Wh,
                                               const float* __restrict__ bh,
                                               const float* __restrict__ Wc,
                                               const float* __restrict__ bc,
                                               float* __restrict__ o_lin,
                                               __bf16* __restrict__ o_bf16, int t) {
    const int b = blockIdx.x >> 1, dh = blockIdx.x & 1;
    const int tid = threadIdx.x;
    __shared__ float hl[512];
    __shared__ float sc[64];
    __shared__ float ctx[512];

    if (tid < 128) *(float4*)&hl[tid * 4] = *(const float4*)&hcur[(size_t)b * 512 + tid * 4];
    __syncthreads();

    // scores: 4 threads per s
    {
        int s = tid >> 2, q = tid & 3;
        const float* ep = encproj + ((size_t)b * 64 + s) * 512 + q * 128;
        float acc = 0;
#pragma unroll 8
        for (int k = 0; k < 128; k += 4) {
            float4 e4 = *(const float4*)&ep[k];
            float4 h4 = *(const float4*)&hl[q * 128 + k];
            acc += dot4(e4, h4);
        }
        acc += __shfl_xor(acc, 1);
        acc += __shfl_xor(acc, 2);
        if (q == 0) sc[s] = acc;
    }
    __syncthreads();

    if (tid < 64) {
        float v = sc[tid];
        v = (mask[b * 64 + tid] > 0.f) ? v : -1e9f;
        float m = v;
#pragma unroll
        for (int d = 1; d < 64; d <<= 1) m = fmaxf(m, __shfl_xor(m, d));
        float e = __expf(v - m);
        float sum = e;
#pragma unroll
        for (int d = 1; d < 64; d <<= 1) sum += __shfl_xor(sum, d);
        sc[tid] = e / sum;
    }
    __syncthreads();

    // context
#pragma unroll
    for (int rep = 0; rep < 2; ++rep) {
        int e = rep * 256 + tid;
        float a = 0;
        for (int si = 0; si < 64; ++si) a += sc[si] * enc[((size_t)b * 64 + si) * 512 + e];
        ctx[e] = a;
    }
    __syncthreads();

    // o[d] = tanh(h.W_h[d] + b_h[d] + ctx.W_c[d] + b_c[d])
    {
        int d = dh * 256 + tid;
        const float* whr = Wh + (size_t)d * 512;
        const float* wcr = Wc + (size_t)d * 512;
        float acc = bh[d] + bc[d];
#pragma unroll 4
        for (int k = 0; k < 512; k += 4) {
            float4 w1 = *(const float4*)&whr[k];
            float4 h4 = *(const float4*)&hl[k];
            float4 w2 = *(const float4*)&wcr[k];
            float4 c4 = *(const float4*)&ctx[k];
            acc += dot4(w1, h4) + dot4(w2, c4);
        }
        float o = tanhf(acc);
        o_lin[(size_t)b * 512 + d] = o;
        o_bf16[((size_t)b * 64 + t) * 512 + d] = (__bf16)o;
    }
}

extern "C" void kernel_launch(void* const* d_in, const int* in_sizes, int n_in,
                              void* d_out, int out_size, void* d_ws, size_t ws_size,
                              hipStream_t stream) {
    const int* trg = (const int*)d_in[0];
    const float* enc = (const float*)d_in[1];
    const float* init_h = (const float*)d_in[2];  // [1,B,R] == [32][512]
    const float* mask = (const float*)d_in[3];
    const float* embW = (const float*)d_in[4];
    const float* Wih = (const float*)d_in[5];
    const float* Whh = (const float*)d_in[6];
    const float* bih = (const float*)d_in[7];
    const float* bhh = (const float*)d_in[8];
    const float* Wa = (const float*)d_in[9];
    const float* Wh = (const float*)d_in[10];
    const float* bh = (const float*)d_in[11];
    const float* Wc = (const float*)d_in[12];
    const float* bc = (const float*)d_in[13];
    const float* blog = (const float*)d_in[14];
    float* out = (float*)d_out;

    // workspace carve (~60 MB)
    char* w = (char*)d_ws;
    auto alloc = [&](size_t bytes) { char* p = w; w += (bytes + 255) & ~(size_t)255; return p; };
    __bf16* embW_bf = (__bf16*)alloc((size_t)V_ * D_ * 2);      // 32.77 MB
    __bf16* Wih_bf  = (__bf16*)alloc((size_t)G3_ * 1024 * 2);   // 3.15 MB
    __bf16* Wa_bf   = (__bf16*)alloc((size_t)R_ * E_ * 2);      // 0.52 MB
    __bf16* enc_bf  = (__bf16*)alloc((size_t)BT_ * E_ * 2);     // 2.10 MB
    __bf16* emb_bf  = (__bf16*)alloc((size_t)BT_ * D_ * 2);     // 2.10 MB
    float* gxe      = (float*)alloc((size_t)T_ * G3_ * B_ * 4); // 12.58 MB
    float* encproj  = (float*)alloc((size_t)BT_ * R_ * 4);      // 4.19 MB
    float* hbuf0    = (float*)alloc((size_t)B_ * R_ * 4);
    float* hbuf1    = (float*)alloc((size_t)B_ * R_ * 4);
    float* o_lin    = (float*)alloc((size_t)B_ * D_ * 4);
    __bf16* o_bf    = (__bf16*)alloc((size_t)BT_ * D_ * 2);     // 2.10 MB

    // 1) converts
    k_convert_bf16<<<(V_ * D_ / 8 + 255) / 256, 256, 0, stream>>>(embW, embW_bf, V_ * D_ / 8);
    k_convert_bf16<<<(G3_ * 1024 / 8 + 255) / 256, 256, 0, stream>>>(Wih, Wih_bf, G3_ * 1024 / 8);
    k_convert_bf16<<<(R_ * E_ / 8 + 255) / 256, 256, 0, stream>>>(Wa, Wa_bf, R_ * E_ / 8);
    k_convert_bf16<<<(BT_ * E_ / 8 + 255) / 256, 256, 0, stream>>>(enc, enc_bf, BT_ * E_ / 8);

    // 2) gather embedding rows
    k_gather_emb<<<(BT_ * 64) / 256, 256, 0, stream>>>(trg, embW_bf, emb_bf);

    // 3) gx_emb = emb @ W_ih[:, :512]^T + b_ih -> scatter [t][j][b]
    k_gemm_bf16<<<(BT_ / 128) * (G3_ / 128), 256, 0, stream>>>(
        emb_bf, Wih_bf, bih, gxe, BT_, G3_, 512, 512, 1024, 1);

    // 4) enc_proj = enc @ W_a^T -> row-major [2048][512]
    k_gemm_bf16<<<(BT_ / 128) * (R_ / 128), 256, 0, stream>>>(
        enc_bf, Wa_bf, nullptr, encproj, BT_, R_, 512, 512, 512, 0);

    // 5) recurrence
    hipMemsetAsync(o_lin, 0, (size_t)B_ * D_ * 4, stream);
    for (int t = 0; t < T_; ++t) {
        const float* hsrc = (t == 0) ? init_h : ((t & 1) ? hbuf0 : hbuf1);
        float* hdst = (t & 1) ? hbuf1 : hbuf0;
        k_stepA<<<128, 512, 0, stream>>>(hsrc, o_lin, Wih, Whh, bhh,
                                         gxe + (size_t)t * G3_ * B_, hdst);
        k_stepB<<<64, 256, 0, stream>>>(hdst, encproj, enc, mask, Wh, bh, Wc, bc,
                                        o_lin, o_bf, t);
    }

    // 6) logits = o @ emb_W^T + b_logits  (M=2048, N=32000, K=512)
    k_gemm_bf16<<<(BT_ / 128) * (V_ / 128), 256, 0, stream>>>(
        o_bf, embW_bf, blog, out, BT_, V_, 512, 512, 512, 0);
}